// Round 19
// baseline (1726.850 us; speedup 1.0000x reference)
//
#include <hip/hip_runtime.h>
#include <math.h>

#define N_NODES 50000
#define E_EDGES 800000
#define KD 128
#define RT_TILES 3125   // N_NODES / 16 (exact)
#define CELL_STRIDE 512 // 128 rowblocks * 4 waves
#define CELL_BLOCKS 1024
#define NBUCKETS 196    // ceil(50000/256) dst>>8 buckets
#define FB_CHUNK 3125   // edges per fill_bucket/hist block (256 blocks)

typedef __attribute__((ext_vector_type(8))) short bf16x8;
typedef __attribute__((ext_vector_type(4))) float f32x4;

__device__ __forceinline__ float fsig(float x) { return 1.f / (1.f + __expf(-x)); }
__device__ __forceinline__ float ftanh(float x) { return 1.f - 2.f / (1.f + __expf(2.f * x)); }

__device__ __forceinline__ unsigned short f2bf(float f) {
    unsigned u = __float_as_uint(f);
    return (unsigned short)((u + 0x7FFFu + ((u >> 16) & 1u)) >> 16);
}
__device__ __forceinline__ float bf2f(unsigned short b) {
    return __uint_as_float(((unsigned)b) << 16);
}
__device__ __forceinline__ bf16x8 ldfrag(const unsigned short* p) {
    return *(const bf16x8*)(const void*)p;
}
__device__ __forceinline__ void stage_frag(const unsigned short* g, unsigned short* l) {
    __builtin_amdgcn_global_load_lds(
        (const __attribute__((address_space(1))) unsigned int*)g,
        (__attribute__((address_space(3))) unsigned int*)l, 16, 0, 0);
}
// XCD-aware decode: 8 colgroup-sharers of a rowblock get ids spaced 8 apart
// (same id%8 -> same XCD, co-resident). [R9 measured: FETCH 125 -> 26.8 MB]
// R13: NO nt-stores (L2 merges partial lines). R14: NO setprio (VGPR cliff).
__device__ __forceinline__ void cell_decode(int id, int& x, int& y) {
    y = ((id >> 6) << 3) + (id & 7);   // rowblock 0..127
    x = (id >> 3) & 7;                 // colgroup 0..7
}

// Device-scope grid barrier (all 1024 blocks resident via launch_bounds(256,4)).
__device__ __forceinline__ void grid_barrier(int* cnt, int* gen) {
    __syncthreads();
    if (threadIdx.x == 0) {
        int g = __hip_atomic_load(gen, __ATOMIC_RELAXED, __HIP_MEMORY_SCOPE_AGENT);
        __threadfence();
        int old = __hip_atomic_fetch_add(cnt, 1, __ATOMIC_ACQ_REL, __HIP_MEMORY_SCOPE_AGENT);
        if (old == CELL_BLOCKS - 1) {
            __hip_atomic_store(cnt, 0, __ATOMIC_RELAXED, __HIP_MEMORY_SCOPE_AGENT);
            __hip_atomic_store(gen, g + 1, __ATOMIC_RELEASE, __HIP_MEMORY_SCOPE_AGENT);
        } else {
            while (__hip_atomic_load(gen, __ATOMIC_ACQUIRE, __HIP_MEMORY_SCOPE_AGENT) == g)
                __builtin_amdgcn_s_sleep(16);
        }
        __threadfence();
    }
    __syncthreads();
}

// ---------------------------------------------------------------------------
// Merged prologue: cvt_xh | cvt_weights | fuse_wg_wih | bucket-histogram
// ---------------------------------------------------------------------------
#define PB_XH 12500
#define PB_W  12684
#define PB_F  13068
#define PB_TOT 13324
__global__ __launch_bounds__(256) void prologue(
        const float* __restrict__ x, const float* __restrict__ H,
        const float* __restrict__ gru_whh, const float* __restrict__ lstm_wih,
        const float* __restrict__ lstm_whh, const float* __restrict__ lin_w,
        const float* __restrict__ ggc_w, const float* __restrict__ gru_wih,
        const int* __restrict__ ei,
        unsigned short* __restrict__ hb, unsigned short* __restrict__ Hxb,
        unsigned short* __restrict__ whhb, unsigned short* __restrict__ lwihb,
        unsigned short* __restrict__ lwhhb, unsigned short* __restrict__ linwb,
        unsigned short* __restrict__ WfT, int* __restrict__ bucketTotal) {
    const int b = blockIdx.x;
    if (b < PB_XH) {
        int t = b * 256 + threadIdx.x;
        const int n4 = N_NODES * KD / 4;
        const float* in; unsigned short* out; int idx;
        if (t < n4) { in = x; out = hb; idx = t; }
        else { in = H; out = Hxb; idx = t - n4; }
        float4 v = ((const float4*)in)[idx];
        ushort4 o;
        o.x = f2bf(v.x); o.y = f2bf(v.y); o.z = f2bf(v.z); o.w = f2bf(v.w);
        ((ushort4*)out)[idx] = o;
    } else if (b < PB_W) {
        int t = (b - PB_XH) * 256 + threadIdx.x;
        const float* in; unsigned short* out; int idx;
        if      (t < 12288)  { in = gru_whh;  out = whhb;  idx = t; }
        else if (t < 28672)  { in = lstm_wih; out = lwihb; idx = t - 12288; }
        else if (t < 45056)  { in = lstm_whh; out = lwhhb; idx = t - 28672; }
        else if (t < 47104)  { in = lin_w;    out = linwb; idx = t - 45056; }
        else return;
        float4 v = ((const float4*)in)[idx];
        ushort4 o;
        o.x = f2bf(v.x); o.y = f2bf(v.y); o.z = f2bf(v.z); o.w = f2bf(v.w);
        ((ushort4*)out)[idx] = o;
    } else if (b < PB_F) {
        int j = b - PB_W;
        __shared__ float wi[128];
        int k = threadIdx.x & 127;
        int l = threadIdx.x >> 7;
        if (threadIdx.x < 128) wi[k] = gru_wih[j * 128 + k];
        __syncthreads();
        const float* wg = ggc_w + l * 16384 + k * 128;
        float s = 0.f;
#pragma unroll 8
        for (int c = 0; c < 128; c += 4) {
            float4 a = *(const float4*)(wg + c);
            s += a.x * wi[c] + a.y * wi[c + 1] + a.z * wi[c + 2] + a.w * wi[c + 3];
        }
        WfT[((size_t)l * 384 + j) * 128 + k] = f2bf(s);
    } else {
        __shared__ int hist[NBUCKETS];
        const int t = threadIdx.x;
        const int e0 = (b - PB_F) * FB_CHUNK;
        const int e1 = min(e0 + FB_CHUNK, E_EDGES);
        for (int i = t; i < NBUCKETS; i += 256) hist[i] = 0;
        __syncthreads();
        for (int e = e0 + t; e < e1; e += 256)
            atomicAdd(&hist[ei[E_EDGES + e] >> 8], 1);
        __syncthreads();
        for (int i = t; i < NBUCKETS; i += 256)
            if (hist[i]) atomicAdd(&bucketTotal[i], hist[i]);
    }
}

// ---------------------------------------------------------------------------
// Tiny scan: 196 bucket totals -> bucketBase (=rowptr[256b]) and fill cursors.
// ---------------------------------------------------------------------------
__global__ __launch_bounds__(256) void scan_buckets(const int* __restrict__ bucketTotal,
                                                    int* __restrict__ bucketBase,
                                                    int* __restrict__ bucketCur) {
    __shared__ int part[256];
    const int t = threadIdx.x;
    int v = (t < NBUCKETS) ? bucketTotal[t] : 0;
    part[t] = v;
    __syncthreads();
#pragma unroll
    for (int off = 1; off < 256; off <<= 1) {
        int u = (t >= off) ? part[t - off] : 0;
        __syncthreads();
        part[t] += u;
        __syncthreads();
    }
    if (t < NBUCKETS) {
        int base = part[t] - v;
        bucketBase[t] = base;
        bucketCur[t] = base;
    }
    if (t == NBUCKETS - 1) bucketBase[NBUCKETS] = part[t];
}

// ---------------------------------------------------------------------------
// Bucketed fill pass B: scatter edges into coarse dst>>8 staging regions.
// ---------------------------------------------------------------------------
__global__ __launch_bounds__(256) void fill_bucket(const int* __restrict__ ei,
                                                   const float* __restrict__ ew,
                                                   int* __restrict__ bucketCur,
                                                   int2* __restrict__ stage_sw,
                                                   int* __restrict__ stage_dst) {
    __shared__ int hist[NBUCKETS];
    __shared__ int base[NBUCKETS];
    __shared__ int loff[NBUCKETS];
    const int t = threadIdx.x;
    const int e0 = blockIdx.x * FB_CHUNK;
    const int e1 = min(e0 + FB_CHUNK, E_EDGES);
    for (int i = t; i < NBUCKETS; i += 256) { hist[i] = 0; loff[i] = 0; }
    __syncthreads();
    for (int e = e0 + t; e < e1; e += 256)
        atomicAdd(&hist[ei[E_EDGES + e] >> 8], 1);
    __syncthreads();
    for (int i = t; i < NBUCKETS; i += 256)
        base[i] = hist[i] ? atomicAdd(&bucketCur[i], hist[i]) : 0;
    __syncthreads();
    for (int e = e0 + t; e < e1; e += 256) {
        int dst = ei[E_EDGES + e];
        int bk = dst >> 8;
        int pos = base[bk] + atomicAdd(&loff[bk], 1);
        int2 pk;
        pk.x = ei[e];
        pk.y = __float_as_int(ew[e]);
        stage_sw[pos] = pk;
        stage_dst[pos] = dst;
    }
}

// ---------------------------------------------------------------------------
// Bucketed fill pass C: one block per bucket; LDS degree scan writes rowptr,
// then finalizes sEdge (single-owner region -> full-line L2 assembly).
// ---------------------------------------------------------------------------
__global__ __launch_bounds__(256) void fill_final(const int* __restrict__ bucketBase,
                                                  const int2* __restrict__ stage_sw,
                                                  const int* __restrict__ stage_dst,
                                                  int2* __restrict__ sEdge,
                                                  int* __restrict__ rowptr) {
    __shared__ int cnt[256];
    __shared__ int off[256];
    const int b = blockIdx.x;
    const int t = threadIdx.x;
    const int node0 = b << 8;
    const int e0 = bucketBase[b];
    const int e1 = bucketBase[b + 1];
    cnt[t] = 0;
    __syncthreads();
    for (int e = e0 + t; e < e1; e += 256)
        atomicAdd(&cnt[stage_dst[e] & 255], 1);
    __syncthreads();
    int v = cnt[t];
    off[t] = v;
    __syncthreads();
#pragma unroll
    for (int o = 1; o < 256; o <<= 1) {
        int u = (t >= o) ? off[t - o] : 0;
        __syncthreads();
        off[t] += u;
        __syncthreads();
    }
    const int excl = off[t] - v;
    if (node0 + t < N_NODES) rowptr[node0 + t] = e0 + excl;
    if (b == NBUCKETS - 1 && t == 0) rowptr[N_NODES] = e1;
    cnt[t] = excl;
    __syncthreads();
    for (int e = e0 + t; e < e1; e += 256) {
        int dl = stage_dst[e] & 255;
        int pos = e0 + atomicAdd(&cnt[dl], 1);
        sEdge[pos] = stage_sw[e];
    }
}

// ---------------------------------------------------------------------------
// Mega-kernel phase bodies (proven R17 structures)
// ---------------------------------------------------------------------------
__device__ void gather_phase(const unsigned short* m, const int* rowptr,
                             const int2* sEdge, unsigned short* agg) {
    const int lane = threadIdx.x & 63;
    const int q = lane >> 4, li = lane & 15;
    const int f0 = li << 3;
    for (int wid = (blockIdx.x * 256 + threadIdx.x) >> 6; wid < N_NODES; wid += 4096) {
        int e0 = rowptr[wid], e1 = rowptr[wid + 1];
        float acc[8] = {0.f, 0.f, 0.f, 0.f, 0.f, 0.f, 0.f, 0.f};
        int e = e0 + q;
        bf16x8 v = {0, 0, 0, 0, 0, 0, 0, 0};
        float w0 = 0.f;
        if (e < e1) {
            int2 pk0 = sEdge[e];
            w0 = __int_as_float(pk0.y);
            v = ldfrag(m + (size_t)pk0.x * KD + f0);
        }
        int2 pk1 = make_int2(0, 0);
        if (e + 4 < e1) pk1 = sEdge[e + 4];
        for (; e < e1; e += 4) {
            float wc = w0;
            bf16x8 vc = v;
            if (e + 4 < e1) {
                w0 = __int_as_float(pk1.y);
                v = ldfrag(m + (size_t)pk1.x * KD + f0);
            }
            if (e + 8 < e1) pk1 = sEdge[e + 8];
#pragma unroll
            for (int j = 0; j < 8; ++j)
                acc[j] += wc * bf2f((unsigned short)vc[j]);
        }
#pragma unroll
        for (int j = 0; j < 8; ++j) {
            acc[j] += __shfl_xor(acc[j], 16, 64);
            acc[j] += __shfl_xor(acc[j], 32, 64);
        }
        if (q == 0) {
            bf16x8 o;
#pragma unroll
            for (int j = 0; j < 8; ++j) o[j] = (short)f2bf(acc[j]);
            *(bf16x8*)(agg + (size_t)wid * KD + f0) = o;
        }
    }
}

__device__ void gru_phase(unsigned short* lds,
                          const unsigned short* Agg, const unsigned short* Hin,
                          unsigned short* Hout, const unsigned short* Wih,
                          const unsigned short* Whh, const float* bih,
                          const float* bhh) {
    int cg, rb;
    cell_decode(blockIdx.x, cg, rb);
    const int lane = threadIdx.x & 63, wave = threadIdx.x >> 6;
    const int rl = lane & 15, kg = lane >> 4;
    const int col0 = cg * 16;
    for (int q = wave; q < 24; q += 4) {
        int s = q >> 2, kk = q & 3;
        const unsigned short* src = (s < 3 ? Wih + (size_t)s * 128 * KD
                                           : Whh + (size_t)(s - 3) * 128 * KD)
                                    + (size_t)(col0 + rl) * KD + kk * 32 + kg * 8;
        stage_frag(src, lds + q * 512);
    }
    __syncthreads();
    const int col = col0 + rl;
    const float b_ir = bih[col], b_iz = bih[128 + col], b_in = bih[256 + col];
    const float b_hr = bhh[col], b_hz = bhh[128 + col], b_hn = bhh[256 + col];
    int rt = rb * 4 + wave;   // <= 511 always
    bf16x8 a1[4], a2[4];
    unsigned short hvc[4];
#pragma unroll
    for (int kk = 0; kk < 4; ++kk) {
        a1[kk] = ldfrag(Agg + ((size_t)rt * 16 + rl) * KD + kk * 32 + kg * 8);
        a2[kk] = ldfrag(Hin + ((size_t)rt * 16 + rl) * KD + kk * 32 + kg * 8);
    }
#pragma unroll
    for (int p = 0; p < 4; ++p)
        hvc[p] = Hin[(size_t)(rt * 16 + kg * 4 + p) * KD + col];
    while (rt < RT_TILES) {
        const int rtn = rt + CELL_STRIDE;
        bf16x8 n1[4], n2[4];
        unsigned short hvn[4];
        if (rtn < RT_TILES) {
#pragma unroll
            for (int kk = 0; kk < 4; ++kk) {
                n1[kk] = ldfrag(Agg + ((size_t)rtn * 16 + rl) * KD + kk * 32 + kg * 8);
                n2[kk] = ldfrag(Hin + ((size_t)rtn * 16 + rl) * KD + kk * 32 + kg * 8);
            }
#pragma unroll
            for (int p = 0; p < 4; ++p)
                hvn[p] = Hin[(size_t)(rtn * 16 + kg * 4 + p) * KD + col];
        }
        f32x4 ir = {0.f,0.f,0.f,0.f}, iz = ir, in_ = ir, hr = ir, hz = ir, hn = ir;
#pragma unroll
        for (int kk = 0; kk < 4; ++kk) {
            ir  = __builtin_amdgcn_mfma_f32_16x16x32_bf16(a1[kk], ldfrag(lds + (0*4+kk)*512 + lane*8), ir,  0, 0, 0);
            iz  = __builtin_amdgcn_mfma_f32_16x16x32_bf16(a1[kk], ldfrag(lds + (1*4+kk)*512 + lane*8), iz,  0, 0, 0);
            in_ = __builtin_amdgcn_mfma_f32_16x16x32_bf16(a1[kk], ldfrag(lds + (2*4+kk)*512 + lane*8), in_, 0, 0, 0);
            hr  = __builtin_amdgcn_mfma_f32_16x16x32_bf16(a2[kk], ldfrag(lds + (3*4+kk)*512 + lane*8), hr,  0, 0, 0);
            hz  = __builtin_amdgcn_mfma_f32_16x16x32_bf16(a2[kk], ldfrag(lds + (4*4+kk)*512 + lane*8), hz,  0, 0, 0);
            hn  = __builtin_amdgcn_mfma_f32_16x16x32_bf16(a2[kk], ldfrag(lds + (5*4+kk)*512 + lane*8), hn,  0, 0, 0);
        }
#pragma unroll
        for (int p = 0; p < 4; ++p) {
            int row = rt * 16 + kg * 4 + p;
            float r = fsig(ir[p] + b_ir + hr[p] + b_hr);
            float z = fsig(iz[p] + b_iz + hz[p] + b_hz);
            float nc = ftanh(in_[p] + b_in + r * (hn[p] + b_hn));
            float hv = bf2f(hvc[p]);
            Hout[(size_t)row * KD + col] = f2bf((1.f - z) * nc + z * hv);
        }
        rt = rtn;
#pragma unroll
        for (int kk = 0; kk < 4; ++kk) { a1[kk] = n1[kk]; a2[kk] = n2[kk]; }
#pragma unroll
        for (int p = 0; p < 4; ++p) hvc[p] = hvn[p];
    }
}

__device__ void lstm_phase(unsigned short* lds,
                           const unsigned short* Hh, const unsigned short* Hx,
                           const float* Cx, const unsigned short* Wih,
                           const unsigned short* Whh, const float* bih,
                           const float* bhh, float* h_out, float* c_out,
                           unsigned short* Hrelu) {
    int cg, rb;
    cell_decode(blockIdx.x, cg, rb);
    const int lane = threadIdx.x & 63, wave = threadIdx.x >> 6;
    const int rl = lane & 15, kg = lane >> 4;
    const int col0 = cg * 16;
    for (int q = wave; q < 32; q += 4) {
        int s = q >> 2, kk = q & 3;
        const unsigned short* src = (s < 4 ? Wih + (size_t)s * 128 * KD
                                           : Whh + (size_t)(s - 4) * 128 * KD)
                                    + (size_t)(col0 + rl) * KD + kk * 32 + kg * 8;
        stage_frag(src, lds + q * 512);
    }
    __syncthreads();
    const int col = col0 + rl;
    const float b_i = bih[col] + bhh[col];
    const float b_f = bih[128 + col] + bhh[128 + col];
    const float b_g = bih[256 + col] + bhh[256 + col];
    const float b_o = bih[384 + col] + bhh[384 + col];
    int rt = rb * 4 + wave;
    bf16x8 a1[4], a2[4];
    float cpre[4];
#pragma unroll
    for (int kk = 0; kk < 4; ++kk) {
        a1[kk] = ldfrag(Hh + ((size_t)rt * 16 + rl) * KD + kk * 32 + kg * 8);
        a2[kk] = ldfrag(Hx + ((size_t)rt * 16 + rl) * KD + kk * 32 + kg * 8);
    }
#pragma unroll
    for (int p = 0; p < 4; ++p)
        cpre[p] = Cx[(size_t)(rt * 16 + kg * 4 + p) * KD + col];
    while (rt < RT_TILES) {
        const int rtn = rt + CELL_STRIDE;
        bf16x8 n1[4], n2[4];
        float cnx[4];
        if (rtn < RT_TILES) {
#pragma unroll
            for (int kk = 0; kk < 4; ++kk) {
                n1[kk] = ldfrag(Hh + ((size_t)rtn * 16 + rl) * KD + kk * 32 + kg * 8);
                n2[kk] = ldfrag(Hx + ((size_t)rtn * 16 + rl) * KD + kk * 32 + kg * 8);
            }
#pragma unroll
            for (int p = 0; p < 4; ++p)
                cnx[p] = Cx[(size_t)(rtn * 16 + kg * 4 + p) * KD + col];
        }
        f32x4 gi = {0.f,0.f,0.f,0.f}, gf = gi, gg = gi, go = gi;
        f32x4 hi = gi, hf = gi, hg = gi, ho = gi;
#pragma unroll
        for (int kk = 0; kk < 4; ++kk) {
            gi = __builtin_amdgcn_mfma_f32_16x16x32_bf16(a1[kk], ldfrag(lds + (0*4+kk)*512 + lane*8), gi, 0, 0, 0);
            gf = __builtin_amdgcn_mfma_f32_16x16x32_bf16(a1[kk], ldfrag(lds + (1*4+kk)*512 + lane*8), gf, 0, 0, 0);
            gg = __builtin_amdgcn_mfma_f32_16x16x32_bf16(a1[kk], ldfrag(lds + (2*4+kk)*512 + lane*8), gg, 0, 0, 0);
            go = __builtin_amdgcn_mfma_f32_16x16x32_bf16(a1[kk], ldfrag(lds + (3*4+kk)*512 + lane*8), go, 0, 0, 0);
            hi = __builtin_amdgcn_mfma_f32_16x16x32_bf16(a2[kk], ldfrag(lds + (4*4+kk)*512 + lane*8), hi, 0, 0, 0);
            hf = __builtin_amdgcn_mfma_f32_16x16x32_bf16(a2[kk], ldfrag(lds + (5*4+kk)*512 + lane*8), hf, 0, 0, 0);
            hg = __builtin_amdgcn_mfma_f32_16x16x32_bf16(a2[kk], ldfrag(lds + (6*4+kk)*512 + lane*8), hg, 0, 0, 0);
            ho = __builtin_amdgcn_mfma_f32_16x16x32_bf16(a2[kk], ldfrag(lds + (7*4+kk)*512 + lane*8), ho, 0, 0, 0);
        }
#pragma unroll
        for (int p = 0; p < 4; ++p) {
            int row = rt * 16 + kg * 4 + p;
            size_t idx = (size_t)row * KD + col;
            float ig = fsig(gi[p] + hi[p] + b_i);
            float fg = fsig(gf[p] + hf[p] + b_f);
            float gv = ftanh(gg[p] + hg[p] + b_g);
            float og = fsig(go[p] + ho[p] + b_o);
            float c = fg * cpre[p] + ig * gv;
            float hn = og * ftanh(c);
            c_out[idx] = c;
            h_out[idx] = hn;
            Hrelu[idx] = f2bf(fmaxf(hn, 0.f));
        }
        rt = rtn;
#pragma unroll
        for (int kk = 0; kk < 4; ++kk) { a1[kk] = n1[kk]; a2[kk] = n2[kk]; }
#pragma unroll
        for (int p = 0; p < 4; ++p) cpre[p] = cnx[p];
    }
}

__device__ void head_phase(unsigned short* lds,
                           const unsigned short* Hr, const unsigned short* LinW,
                           const float* lin_b, float* Out) {
    const int lane = threadIdx.x & 63, wave = threadIdx.x >> 6;
    const int rl = lane & 15, kg = lane >> 4;
    for (int f = wave; f < 16; f += 4) {
        int jt = f >> 2, kk = f & 3;
        stage_frag(LinW + (size_t)(jt * 16 + rl) * KD + kk * 32 + kg * 8, lds + f * 512);
    }
    __syncthreads();
    for (int rt = blockIdx.x * 4 + wave; rt < RT_TILES; rt += 4096) {
        bf16x8 a[4];
#pragma unroll
        for (int kk = 0; kk < 4; ++kk)
            a[kk] = ldfrag(Hr + ((size_t)rt * 16 + rl) * KD + kk * 32 + kg * 8);
#pragma unroll
        for (int jt = 0; jt < 4; ++jt) {
            f32x4 acc = {0.f, 0.f, 0.f, 0.f};
#pragma unroll
            for (int kk = 0; kk < 4; ++kk)
                acc = __builtin_amdgcn_mfma_f32_16x16x32_bf16(
                    a[kk], ldfrag(lds + (jt * 4 + kk) * 512 + lane * 8), acc, 0, 0, 0);
            int col = jt * 16 + rl;
            float b = lin_b[col];
#pragma unroll
            for (int p = 0; p < 4; ++p)
                Out[(size_t)(rt * 16 + kg * 4 + p) * 64 + col] = acc[p] + b;
        }
    }
}

// ---------------------------------------------------------------------------
// Mega: gather0 | gru0 | gather1 | gru1 | lstm | head with grid barriers.
// 1024 blocks all-resident (launch_bounds(256,4): <=128 VGPR, 32KB LDS).
// ---------------------------------------------------------------------------
__global__ __launch_bounds__(256, 4) void mega(
        unsigned short* hb, unsigned short* hb1, const unsigned short* Hxb,
        unsigned short* aggb, unsigned short* mb,
        const unsigned short* WfT, const unsigned short* whhb,
        const unsigned short* lwihb, const unsigned short* lwhhb,
        const unsigned short* linwb,
        const int* rowptr, const int2* sEdge,
        const float* gru_bih, const float* gru_bhh,
        const float* Cx, const float* lstm_bih, const float* lstm_bhh,
        const float* lin_b,
        float* h_out, float* c_out, float* out_head,
        int* bar_cnt, int* bar_gen) {
    __shared__ unsigned short lds[32 * 512];   // 32 KB, reused per phase
    gather_phase(hb, rowptr, sEdge, aggb);
    grid_barrier(bar_cnt, bar_gen);
    gru_phase(lds, aggb, hb, hb1, WfT, whhb, gru_bih, gru_bhh);
    grid_barrier(bar_cnt, bar_gen);
    gather_phase(hb1, rowptr, sEdge, aggb);
    grid_barrier(bar_cnt, bar_gen);
    gru_phase(lds, aggb, hb1, hb, WfT + (size_t)384 * KD, whhb, gru_bih, gru_bhh);
    grid_barrier(bar_cnt, bar_gen);
    lstm_phase(lds, hb, Hxb, Cx, lwihb, lwhhb, lstm_bih, lstm_bhh,
               h_out, c_out, mb);
    grid_barrier(bar_cnt, bar_gen);
    head_phase(lds, mb, linwb, lin_b, out_head);
}

extern "C" void kernel_launch(void* const* d_in, const int* in_sizes, int n_in,
                              void* d_out, int out_size, void* d_ws, size_t ws_size,
                              hipStream_t stream) {
    const float* x        = (const float*)d_in[0];
    const int*   ei       = (const int*)d_in[1];
    const float* ew       = (const float*)d_in[2];
    const float* H        = (const float*)d_in[3];
    const float* C        = (const float*)d_in[4];
    const float* ggc_w    = (const float*)d_in[5];
    const float* gru_wih  = (const float*)d_in[6];
    const float* gru_whh  = (const float*)d_in[7];
    const float* gru_bih  = (const float*)d_in[8];
    const float* gru_bhh  = (const float*)d_in[9];
    const float* lstm_wih = (const float*)d_in[10];
    const float* lstm_whh = (const float*)d_in[11];
    const float* lstm_bih = (const float*)d_in[12];
    const float* lstm_bhh = (const float*)d_in[13];
    const float* lin_w    = (const float*)d_in[14];
    const float* lin_b    = (const float*)d_in[15];

    float* out_head = (float*)d_out;
    float* h_out = out_head + (size_t)N_NODES * 64;
    float* c_out = h_out + (size_t)N_NODES * KD;

    char* w = (char*)d_ws;
    unsigned short* hb    = (unsigned short*)w; w += (size_t)N_NODES * KD * 2;
    unsigned short* hb1   = (unsigned short*)w; w += (size_t)N_NODES * KD * 2;
    unsigned short* Hxb   = (unsigned short*)w; w += (size_t)N_NODES * KD * 2;
    unsigned short* mb    = (unsigned short*)w; w += (size_t)N_NODES * KD * 2;  // Hrelu
    unsigned short* aggb  = (unsigned short*)w; w += (size_t)N_NODES * KD * 2;  // gathered h
    unsigned short* WfT   = (unsigned short*)w; w += 2 * 384 * KD * 2;          // fused Wg·Wih^T
    unsigned short* whhb  = (unsigned short*)w; w += 384 * KD * 2;
    unsigned short* lwihb = (unsigned short*)w; w += 512 * KD * 2;
    unsigned short* lwhhb = (unsigned short*)w; w += 512 * KD * 2;
    unsigned short* linwb = (unsigned short*)w; w += 64 * KD * 2;
    int*   rowptr      = (int*)w; w += 50304 * 4;
    int*   bucketTotal = (int*)w; w += 256 * 4;   // [200],[201] = barrier cnt/gen
    int*   bucketBase  = (int*)w; w += 256 * 4;
    int*   bucketCur   = (int*)w; w += 256 * 4;
    int2*  sEdge       = (int2*)w; w += (size_t)E_EDGES * 8;
    int2*  stage_sw    = (int2*)w; w += (size_t)E_EDGES * 8;
    int*   stage_dst   = (int*)w; w += (size_t)E_EDGES * 4;
    int*   bar_cnt = bucketTotal + 200;
    int*   bar_gen = bucketTotal + 201;

    dim3 blk(256);

    hipMemsetAsync(bucketTotal, 0, 256 * sizeof(int), stream);   // also zeroes barrier
    prologue<<<PB_TOT, blk, 0, stream>>>(x, H, gru_whh, lstm_wih, lstm_whh, lin_w,
                                         ggc_w, gru_wih, ei,
                                         hb, Hxb, whhb, lwihb, lwhhb, linwb, WfT,
                                         bucketTotal);
    scan_buckets<<<1, blk, 0, stream>>>(bucketTotal, bucketBase, bucketCur);
    fill_bucket<<<256, blk, 0, stream>>>(ei, ew, bucketCur, stage_sw, stage_dst);
    fill_final<<<NBUCKETS, blk, 0, stream>>>(bucketBase, stage_sw, stage_dst,
                                             sEdge, rowptr);
    mega<<<CELL_BLOCKS, blk, 0, stream>>>(hb, hb1, Hxb, aggb, mb,
                                          WfT, whhb, lwihb, lwhhb, linwb,
                                          rowptr, sEdge,
                                          gru_bih, gru_bhh,
                                          C, lstm_bih, lstm_bhh, lin_b,
                                          h_out, c_out, out_head,
                                          bar_cnt, bar_gen);
}

// Round 20
// 262.902 us; speedup vs baseline: 6.5684x; 6.5684x over previous
//
#include <hip/hip_runtime.h>
#include <math.h>

#define N_NODES 50000
#define E_EDGES 800000
#define KD 128
#define RT_TILES 3125   // N_NODES / 16 (exact)
#define CELL_RB 128     // rowblocks in cell kernels (persistent: 4 blocks/CU)
#define CELL_STRIDE (CELL_RB * 4)
#define CELL_BLOCKS 1024
#define NBUCKETS 196    // ceil(50000/256) dst>>8 buckets
#define FB_CHUNK 3125   // edges per fill_bucket/hist block (256 blocks)

typedef __attribute__((ext_vector_type(8))) short bf16x8;
typedef __attribute__((ext_vector_type(4))) float f32x4;

__device__ __forceinline__ float fsig(float x) { return 1.f / (1.f + __expf(-x)); }
__device__ __forceinline__ float ftanh(float x) { return 1.f - 2.f / (1.f + __expf(2.f * x)); }

__device__ __forceinline__ unsigned short f2bf(float f) {
    unsigned u = __float_as_uint(f);
    return (unsigned short)((u + 0x7FFFu + ((u >> 16) & 1u)) >> 16);
}
__device__ __forceinline__ float bf2f(unsigned short b) {
    return __uint_as_float(((unsigned)b) << 16);
}
__device__ __forceinline__ bf16x8 ldfrag(const unsigned short* p) {
    return *(const bf16x8*)(const void*)p;
}
__device__ __forceinline__ void stage_frag(const unsigned short* g, unsigned short* l) {
    __builtin_amdgcn_global_load_lds(
        (const __attribute__((address_space(1))) unsigned int*)g,
        (__attribute__((address_space(3))) unsigned int*)l, 16, 0, 0);
}
// XCD-aware decode: 8 colgroup-sharers of a rowblock get ids spaced 8 apart
// (same id%8 -> same XCD, co-resident). [R9 measured: FETCH 125 -> 26.8 MB]
// R13: NO nt-stores (L2 merges partial lines). R14: NO setprio (VGPR cliff).
// R18: NO mega-fusion (union register pressure -> VGPR 64 + scratch spills, 6x).
__device__ __forceinline__ void cell_decode(int id, int& x, int& y) {
    y = ((id >> 6) << 3) + (id & 7);   // rowblock 0..127
    x = (id >> 3) & 7;                 // colgroup 0..7
}

// ---------------------------------------------------------------------------
// Merged prologue: cvt_xh | cvt_weights | fuse_wg_wih | bucket-histogram
// ---------------------------------------------------------------------------
#define PB_XH 12500
#define PB_W  12684
#define PB_F  13068
#define PB_TOT 13324
__global__ __launch_bounds__(256) void prologue(
        const float* __restrict__ x, const float* __restrict__ H,
        const float* __restrict__ gru_whh, const float* __restrict__ lstm_wih,
        const float* __restrict__ lstm_whh, const float* __restrict__ lin_w,
        const float* __restrict__ ggc_w, const float* __restrict__ gru_wih,
        const int* __restrict__ ei,
        unsigned short* __restrict__ hb, unsigned short* __restrict__ Hxb,
        unsigned short* __restrict__ whhb, unsigned short* __restrict__ lwihb,
        unsigned short* __restrict__ lwhhb, unsigned short* __restrict__ linwb,
        unsigned short* __restrict__ WfT, int* __restrict__ bucketTotal) {
    const int b = blockIdx.x;
    if (b < PB_XH) {
        int t = b * 256 + threadIdx.x;
        const int n4 = N_NODES * KD / 4;
        const float* in; unsigned short* out; int idx;
        if (t < n4) { in = x; out = hb; idx = t; }
        else { in = H; out = Hxb; idx = t - n4; }
        float4 v = ((const float4*)in)[idx];
        ushort4 o;
        o.x = f2bf(v.x); o.y = f2bf(v.y); o.z = f2bf(v.z); o.w = f2bf(v.w);
        ((ushort4*)out)[idx] = o;
    } else if (b < PB_W) {
        int t = (b - PB_XH) * 256 + threadIdx.x;
        const float* in; unsigned short* out; int idx;
        if      (t < 12288)  { in = gru_whh;  out = whhb;  idx = t; }
        else if (t < 28672)  { in = lstm_wih; out = lwihb; idx = t - 12288; }
        else if (t < 45056)  { in = lstm_whh; out = lwhhb; idx = t - 28672; }
        else if (t < 47104)  { in = lin_w;    out = linwb; idx = t - 45056; }
        else return;
        float4 v = ((const float4*)in)[idx];
        ushort4 o;
        o.x = f2bf(v.x); o.y = f2bf(v.y); o.z = f2bf(v.z); o.w = f2bf(v.w);
        ((ushort4*)out)[idx] = o;
    } else if (b < PB_F) {
        int j = b - PB_W;
        __shared__ float wi[128];
        int k = threadIdx.x & 127;
        int l = threadIdx.x >> 7;
        if (threadIdx.x < 128) wi[k] = gru_wih[j * 128 + k];
        __syncthreads();
        const float* wg = ggc_w + l * 16384 + k * 128;
        float s = 0.f;
#pragma unroll 8
        for (int c = 0; c < 128; c += 4) {
            float4 a = *(const float4*)(wg + c);
            s += a.x * wi[c] + a.y * wi[c + 1] + a.z * wi[c + 2] + a.w * wi[c + 3];
        }
        WfT[((size_t)l * 384 + j) * 128 + k] = f2bf(s);
    } else {
        __shared__ int hist[NBUCKETS];
        const int t = threadIdx.x;
        const int e0 = (b - PB_F) * FB_CHUNK;
        const int e1 = min(e0 + FB_CHUNK, E_EDGES);
        for (int i = t; i < NBUCKETS; i += 256) hist[i] = 0;
        __syncthreads();
        for (int e = e0 + t; e < e1; e += 256)
            atomicAdd(&hist[ei[E_EDGES + e] >> 8], 1);
        __syncthreads();
        for (int i = t; i < NBUCKETS; i += 256)
            if (hist[i]) atomicAdd(&bucketTotal[i], hist[i]);
    }
}

// ---------------------------------------------------------------------------
// Tiny scan: 196 bucket totals -> bucketBase (=rowptr[256b]) and fill cursors.
// ---------------------------------------------------------------------------
__global__ __launch_bounds__(256) void scan_buckets(const int* __restrict__ bucketTotal,
                                                    int* __restrict__ bucketBase,
                                                    int* __restrict__ bucketCur) {
    __shared__ int part[256];
    const int t = threadIdx.x;
    int v = (t < NBUCKETS) ? bucketTotal[t] : 0;
    part[t] = v;
    __syncthreads();
#pragma unroll
    for (int off = 1; off < 256; off <<= 1) {
        int u = (t >= off) ? part[t - off] : 0;
        __syncthreads();
        part[t] += u;
        __syncthreads();
    }
    if (t < NBUCKETS) {
        int base = part[t] - v;
        bucketBase[t] = base;
        bucketCur[t] = base;
    }
    if (t == NBUCKETS - 1) bucketBase[NBUCKETS] = part[t];
}

// ---------------------------------------------------------------------------
// Bucketed fill pass B: scatter edges into coarse dst>>8 staging regions.
// ---------------------------------------------------------------------------
__global__ __launch_bounds__(256) void fill_bucket(const int* __restrict__ ei,
                                                   const float* __restrict__ ew,
                                                   int* __restrict__ bucketCur,
                                                   int2* __restrict__ stage_sw,
                                                   int* __restrict__ stage_dst) {
    __shared__ int hist[NBUCKETS];
    __shared__ int base[NBUCKETS];
    __shared__ int loff[NBUCKETS];
    const int t = threadIdx.x;
    const int e0 = blockIdx.x * FB_CHUNK;
    const int e1 = min(e0 + FB_CHUNK, E_EDGES);
    for (int i = t; i < NBUCKETS; i += 256) { hist[i] = 0; loff[i] = 0; }
    __syncthreads();
    for (int e = e0 + t; e < e1; e += 256)
        atomicAdd(&hist[ei[E_EDGES + e] >> 8], 1);
    __syncthreads();
    for (int i = t; i < NBUCKETS; i += 256)
        base[i] = hist[i] ? atomicAdd(&bucketCur[i], hist[i]) : 0;
    __syncthreads();
    for (int e = e0 + t; e < e1; e += 256) {
        int dst = ei[E_EDGES + e];
        int bk = dst >> 8;
        int pos = base[bk] + atomicAdd(&loff[bk], 1);
        int2 pk;
        pk.x = ei[e];
        pk.y = __float_as_int(ew[e]);
        stage_sw[pos] = pk;
        stage_dst[pos] = dst;
    }
}

// ---------------------------------------------------------------------------
// Bucketed fill pass C: one block per bucket; LDS degree scan writes rowptr,
// then finalizes sEdge (single-owner region -> full-line L2 assembly).
// ---------------------------------------------------------------------------
__global__ __launch_bounds__(256) void fill_final(const int* __restrict__ bucketBase,
                                                  const int2* __restrict__ stage_sw,
                                                  const int* __restrict__ stage_dst,
                                                  int2* __restrict__ sEdge,
                                                  int* __restrict__ rowptr) {
    __shared__ int cnt[256];
    __shared__ int off[256];
    const int b = blockIdx.x;
    const int t = threadIdx.x;
    const int node0 = b << 8;
    const int e0 = bucketBase[b];
    const int e1 = bucketBase[b + 1];
    cnt[t] = 0;
    __syncthreads();
    for (int e = e0 + t; e < e1; e += 256)
        atomicAdd(&cnt[stage_dst[e] & 255], 1);
    __syncthreads();
    int v = cnt[t];
    off[t] = v;
    __syncthreads();
#pragma unroll
    for (int o = 1; o < 256; o <<= 1) {
        int u = (t >= o) ? off[t - o] : 0;
        __syncthreads();
        off[t] += u;
        __syncthreads();
    }
    const int excl = off[t] - v;
    if (node0 + t < N_NODES) rowptr[node0 + t] = e0 + excl;
    if (b == NBUCKETS - 1 && t == 0) rowptr[N_NODES] = e1;
    cnt[t] = excl;
    __syncthreads();
    for (int e = e0 + t; e < e1; e += 256) {
        int dl = stage_dst[e] & 255;
        int pos = e0 + atomicAdd(&cnt[dl], 1);
        sEdge[pos] = stage_sw[e];
    }
}

// ---------------------------------------------------------------------------
// gh[n,:] = sum_e w[e]*h[src[e],:]; 4 edges in flight, idx 2-ahead, row 1-ahead
// ---------------------------------------------------------------------------
__global__ __launch_bounds__(256) void gather_agg_bf16(const unsigned short* __restrict__ m,
                                                       const int* __restrict__ rowptr,
                                                       const int2* __restrict__ sEdge,
                                                       unsigned short* __restrict__ agg) {
    int wid = (blockIdx.x * 256 + threadIdx.x) >> 6;
    if (wid >= N_NODES) return;
    int lane = threadIdx.x & 63;
    int q = lane >> 4, li = lane & 15;
    int f0 = li << 3;
    int e0 = rowptr[wid], e1 = rowptr[wid + 1];
    float acc[8] = {0.f, 0.f, 0.f, 0.f, 0.f, 0.f, 0.f, 0.f};
    int e = e0 + q;
    bf16x8 v = {0, 0, 0, 0, 0, 0, 0, 0};
    float w0 = 0.f;
    if (e < e1) {
        int2 pk0 = sEdge[e];
        w0 = __int_as_float(pk0.y);
        v = ldfrag(m + (size_t)pk0.x * KD + f0);
    }
    int2 pk1 = make_int2(0, 0);
    if (e + 4 < e1) pk1 = sEdge[e + 4];
    for (; e < e1; e += 4) {
        float wc = w0;
        bf16x8 vc = v;
        if (e + 4 < e1) {
            w0 = __int_as_float(pk1.y);
            v = ldfrag(m + (size_t)pk1.x * KD + f0);
        }
        if (e + 8 < e1) pk1 = sEdge[e + 8];
#pragma unroll
        for (int j = 0; j < 8; ++j)
            acc[j] += wc * bf2f((unsigned short)vc[j]);
    }
#pragma unroll
    for (int j = 0; j < 8; ++j) {
        acc[j] += __shfl_xor(acc[j], 16, 64);
        acc[j] += __shfl_xor(acc[j], 32, 64);
    }
    if (q == 0) {
        bf16x8 o;
#pragma unroll
        for (int j = 0; j < 8; ++j) o[j] = (short)f2bf(acc[j]);
        *(bf16x8*)(agg + (size_t)wid * KD + f0) = o;
    }
}

// ---------------------------------------------------------------------------
// Fused GRU, col-split 8, XCD-aware persistent grid; pipelined A- AND hv-loads.
// ---------------------------------------------------------------------------
__global__ __launch_bounds__(256) void gru_fused(const unsigned short* __restrict__ Agg,
                                                 const unsigned short* __restrict__ Hin,
                                                 unsigned short* __restrict__ Hout,
                                                 const unsigned short* __restrict__ Wih,
                                                 const unsigned short* __restrict__ Whh,
                                                 const float* __restrict__ bih,
                                                 const float* __restrict__ bhh) {
    int cg, rb;
    cell_decode(blockIdx.x, cg, rb);
    __shared__ unsigned short lds[24 * 512];   // 24 KB
    const int lane = threadIdx.x & 63, wave = threadIdx.x >> 6;
    const int rl = lane & 15, kg = lane >> 4;
    const int col0 = cg * 16;
    for (int q = wave; q < 24; q += 4) {
        int s = q >> 2, kk = q & 3;
        const unsigned short* src = (s < 3 ? Wih + (size_t)s * 128 * KD
                                           : Whh + (size_t)(s - 3) * 128 * KD)
                                    + (size_t)(col0 + rl) * KD + kk * 32 + kg * 8;
        stage_frag(src, lds + q * 512);
    }
    __syncthreads();
    const int col = col0 + rl;
    const float b_ir = bih[col], b_iz = bih[128 + col], b_in = bih[256 + col];
    const float b_hr = bhh[col], b_hz = bhh[128 + col], b_hn = bhh[256 + col];
    int rt = rb * 4 + wave;
    if (rt >= RT_TILES) return;
    bf16x8 a1[4], a2[4];
    unsigned short hvc[4];
#pragma unroll
    for (int kk = 0; kk < 4; ++kk) {
        a1[kk] = ldfrag(Agg + ((size_t)rt * 16 + rl) * KD + kk * 32 + kg * 8);
        a2[kk] = ldfrag(Hin + ((size_t)rt * 16 + rl) * KD + kk * 32 + kg * 8);
    }
#pragma unroll
    for (int p = 0; p < 4; ++p)
        hvc[p] = Hin[(size_t)(rt * 16 + kg * 4 + p) * KD + col];
    while (rt < RT_TILES) {
        const int rtn = rt + CELL_STRIDE;
        bf16x8 n1[4], n2[4];
        unsigned short hvn[4];
        if (rtn < RT_TILES) {
#pragma unroll
            for (int kk = 0; kk < 4; ++kk) {
                n1[kk] = ldfrag(Agg + ((size_t)rtn * 16 + rl) * KD + kk * 32 + kg * 8);
                n2[kk] = ldfrag(Hin + ((size_t)rtn * 16 + rl) * KD + kk * 32 + kg * 8);
            }
#pragma unroll
            for (int p = 0; p < 4; ++p)
                hvn[p] = Hin[(size_t)(rtn * 16 + kg * 4 + p) * KD + col];
        }
        f32x4 ir = {0.f,0.f,0.f,0.f}, iz = ir, in_ = ir, hr = ir, hz = ir, hn = ir;
#pragma unroll
        for (int kk = 0; kk < 4; ++kk) {
            ir  = __builtin_amdgcn_mfma_f32_16x16x32_bf16(a1[kk], ldfrag(lds + (0*4+kk)*512 + lane*8), ir,  0, 0, 0);
            iz  = __builtin_amdgcn_mfma_f32_16x16x32_bf16(a1[kk], ldfrag(lds + (1*4+kk)*512 + lane*8), iz,  0, 0, 0);
            in_ = __builtin_amdgcn_mfma_f32_16x16x32_bf16(a1[kk], ldfrag(lds + (2*4+kk)*512 + lane*8), in_, 0, 0, 0);
            hr  = __builtin_amdgcn_mfma_f32_16x16x32_bf16(a2[kk], ldfrag(lds + (3*4+kk)*512 + lane*8), hr,  0, 0, 0);
            hz  = __builtin_amdgcn_mfma_f32_16x16x32_bf16(a2[kk], ldfrag(lds + (4*4+kk)*512 + lane*8), hz,  0, 0, 0);
            hn  = __builtin_amdgcn_mfma_f32_16x16x32_bf16(a2[kk], ldfrag(lds + (5*4+kk)*512 + lane*8), hn,  0, 0, 0);
        }
#pragma unroll
        for (int p = 0; p < 4; ++p) {
            int row = rt * 16 + kg * 4 + p;
            float r = fsig(ir[p] + b_ir + hr[p] + b_hr);
            float z = fsig(iz[p] + b_iz + hz[p] + b_hz);
            float nc = ftanh(in_[p] + b_in + r * (hn[p] + b_hn));
            float hv = bf2f(hvc[p]);
            Hout[(size_t)row * KD + col] = f2bf((1.f - z) * nc + z * hv);
        }
        rt = rtn;
#pragma unroll
        for (int kk = 0; kk < 4; ++kk) { a1[kk] = n1[kk]; a2[kk] = n2[kk]; }
#pragma unroll
        for (int p = 0; p < 4; ++p) hvc[p] = hvn[p];
    }
}

// ---------------------------------------------------------------------------
// Fused LSTM, col-split 8, XCD-aware persistent grid; pipelined A/Cx loads.
// ---------------------------------------------------------------------------
__global__ __launch_bounds__(256) void lstm_fused(const unsigned short* __restrict__ Hh,
                                                  const unsigned short* __restrict__ Hx,
                                                  const float* __restrict__ Cx,
                                                  const unsigned short* __restrict__ Wih,
                                                  const unsigned short* __restrict__ Whh,
                                                  const float* __restrict__ bih,
                                                  const float* __restrict__ bhh,
                                                  float* __restrict__ h_out,
                                                  float* __restrict__ c_out,
                                                  unsigned short* __restrict__ Hrelu) {
    int cg, rb;
    cell_decode(blockIdx.x, cg, rb);
    __shared__ unsigned short lds[32 * 512];   // 32 KB
    const int lane = threadIdx.x & 63, wave = threadIdx.x >> 6;
    const int rl = lane & 15, kg = lane >> 4;
    const int col0 = cg * 16;
    for (int q = wave; q < 32; q += 4) {
        int s = q >> 2, kk = q & 3;
        const unsigned short* src = (s < 4 ? Wih + (size_t)s * 128 * KD
                                           : Whh + (size_t)(s - 4) * 128 * KD)
                                    + (size_t)(col0 + rl) * KD + kk * 32 + kg * 8;
        stage_frag(src, lds + q * 512);
    }
    __syncthreads();
    const int col = col0 + rl;
    const float b_i = bih[col] + bhh[col];
    const float b_f = bih[128 + col] + bhh[128 + col];
    const float b_g = bih[256 + col] + bhh[256 + col];
    const float b_o = bih[384 + col] + bhh[384 + col];
    int rt = rb * 4 + wave;
    if (rt >= RT_TILES) return;
    bf16x8 a1[4], a2[4];
    float cpre[4];
#pragma unroll
    for (int kk = 0; kk < 4; ++kk) {
        a1[kk] = ldfrag(Hh + ((size_t)rt * 16 + rl) * KD + kk * 32 + kg * 8);
        a2[kk] = ldfrag(Hx + ((size_t)rt * 16 + rl) * KD + kk * 32 + kg * 8);
    }
#pragma unroll
    for (int p = 0; p < 4; ++p)
        cpre[p] = Cx[(size_t)(rt * 16 + kg * 4 + p) * KD + col];
    while (rt < RT_TILES) {
        const int rtn = rt + CELL_STRIDE;
        bf16x8 n1[4], n2[4];
        float cnx[4];
        if (rtn < RT_TILES) {
#pragma unroll
            for (int kk = 0; kk < 4; ++kk) {
                n1[kk] = ldfrag(Hh + ((size_t)rtn * 16 + rl) * KD + kk * 32 + kg * 8);
                n2[kk] = ldfrag(Hx + ((size_t)rtn * 16 + rl) * KD + kk * 32 + kg * 8);
            }
#pragma unroll
            for (int p = 0; p < 4; ++p)
                cnx[p] = Cx[(size_t)(rtn * 16 + kg * 4 + p) * KD + col];
        }
        f32x4 gi = {0.f,0.f,0.f,0.f}, gf = gi, gg = gi, go = gi;
        f32x4 hi = gi, hf = gi, hg = gi, ho = gi;
#pragma unroll
        for (int kk = 0; kk < 4; ++kk) {
            gi = __builtin_amdgcn_mfma_f32_16x16x32_bf16(a1[kk], ldfrag(lds + (0*4+kk)*512 + lane*8), gi, 0, 0, 0);
            gf = __builtin_amdgcn_mfma_f32_16x16x32_bf16(a1[kk], ldfrag(lds + (1*4+kk)*512 + lane*8), gf, 0, 0, 0);
            gg = __builtin_amdgcn_mfma_f32_16x16x32_bf16(a1[kk], ldfrag(lds + (2*4+kk)*512 + lane*8), gg, 0, 0, 0);
            go = __builtin_amdgcn_mfma_f32_16x16x32_bf16(a1[kk], ldfrag(lds + (3*4+kk)*512 + lane*8), go, 0, 0, 0);
            hi = __builtin_amdgcn_mfma_f32_16x16x32_bf16(a2[kk], ldfrag(lds + (4*4+kk)*512 + lane*8), hi, 0, 0, 0);
            hf = __builtin_amdgcn_mfma_f32_16x16x32_bf16(a2[kk], ldfrag(lds + (5*4+kk)*512 + lane*8), hf, 0, 0, 0);
            hg = __builtin_amdgcn_mfma_f32_16x16x32_bf16(a2[kk], ldfrag(lds + (6*4+kk)*512 + lane*8), hg, 0, 0, 0);
            ho = __builtin_amdgcn_mfma_f32_16x16x32_bf16(a2[kk], ldfrag(lds + (7*4+kk)*512 + lane*8), ho, 0, 0, 0);
        }
#pragma unroll
        for (int p = 0; p < 4; ++p) {
            int row = rt * 16 + kg * 4 + p;
            size_t idx = (size_t)row * KD + col;
            float ig = fsig(gi[p] + hi[p] + b_i);
            float fg = fsig(gf[p] + hf[p] + b_f);
            float gv = ftanh(gg[p] + hg[p] + b_g);
            float og = fsig(go[p] + ho[p] + b_o);
            float c = fg * cpre[p] + ig * gv;
            float hn = og * ftanh(c);
            c_out[idx] = c;
            h_out[idx] = hn;
            Hrelu[idx] = f2bf(fmaxf(hn, 0.f));
        }
        rt = rtn;
#pragma unroll
        for (int kk = 0; kk < 4; ++kk) { a1[kk] = n1[kk]; a2[kk] = n2[kk]; }
#pragma unroll
        for (int p = 0; p < 4; ++p) cpre[p] = cnx[p];
    }
}

// ---------------------------------------------------------------------------
// head: out[N][64] = hrelu @ lin_wᵀ + lin_b; pipelined row-stride.
// ---------------------------------------------------------------------------
__global__ __launch_bounds__(256) void head_gemm(const unsigned short* __restrict__ Hr,
                                                 const unsigned short* __restrict__ LinW,
                                                 const float* __restrict__ lin_b,
                                                 float* __restrict__ Out) {
    __shared__ unsigned short wlds[16 * 512];
    const int lane = threadIdx.x & 63, wave = threadIdx.x >> 6;
    const int rl = lane & 15, kg = lane >> 4;
    for (int f = wave; f < 16; f += 4) {
        int jt = f >> 2, kk = f & 3;
        stage_frag(LinW + (size_t)(jt * 16 + rl) * KD + kk * 32 + kg * 8, wlds + f * 512);
    }
    __syncthreads();
    const int stride = gridDim.x << 2;
    int rt = blockIdx.x * 4 + wave;
    if (rt >= RT_TILES) return;
    bf16x8 a[4];
#pragma unroll
    for (int kk = 0; kk < 4; ++kk)
        a[kk] = ldfrag(Hr + ((size_t)rt * 16 + rl) * KD + kk * 32 + kg * 8);
    while (rt < RT_TILES) {
        const int rtn = rt + stride;
        bf16x8 an[4];
        if (rtn < RT_TILES) {
#pragma unroll
            for (int kk = 0; kk < 4; ++kk)
                an[kk] = ldfrag(Hr + ((size_t)rtn * 16 + rl) * KD + kk * 32 + kg * 8);
        }
#pragma unroll
        for (int jt = 0; jt < 4; ++jt) {
            f32x4 acc = {0.f, 0.f, 0.f, 0.f};
#pragma unroll
            for (int kk = 0; kk < 4; ++kk)
                acc = __builtin_amdgcn_mfma_f32_16x16x32_bf16(
                    a[kk], ldfrag(wlds + (jt * 4 + kk) * 512 + lane * 8), acc, 0, 0, 0);
            int col = jt * 16 + rl;
            float b = lin_b[col];
#pragma unroll
            for (int p = 0; p < 4; ++p)
                Out[(size_t)(rt * 16 + kg * 4 + p) * 64 + col] = acc[p] + b;
        }
        rt = rtn;
#pragma unroll
        for (int kk = 0; kk < 4; ++kk) a[kk] = an[kk];
    }
}

extern "C" void kernel_launch(void* const* d_in, const int* in_sizes, int n_in,
                              void* d_out, int out_size, void* d_ws, size_t ws_size,
                              hipStream_t stream) {
    const float* x        = (const float*)d_in[0];
    const int*   ei       = (const int*)d_in[1];
    const float* ew       = (const float*)d_in[2];
    const float* H        = (const float*)d_in[3];
    const float* C        = (const float*)d_in[4];
    const float* ggc_w    = (const float*)d_in[5];
    const float* gru_wih  = (const float*)d_in[6];
    const float* gru_whh  = (const float*)d_in[7];
    const float* gru_bih  = (const float*)d_in[8];
    const float* gru_bhh  = (const float*)d_in[9];
    const float* lstm_wih = (const float*)d_in[10];
    const float* lstm_whh = (const float*)d_in[11];
    const float* lstm_bih = (const float*)d_in[12];
    const float* lstm_bhh = (const float*)d_in[13];
    const float* lin_w    = (const float*)d_in[14];
    const float* lin_b    = (const float*)d_in[15];

    float* out_head = (float*)d_out;
    float* h_out = out_head + (size_t)N_NODES * 64;
    float* c_out = h_out + (size_t)N_NODES * KD;

    char* w = (char*)d_ws;
    unsigned short* hb    = (unsigned short*)w; w += (size_t)N_NODES * KD * 2;
    unsigned short* hb1   = (unsigned short*)w; w += (size_t)N_NODES * KD * 2;
    unsigned short* Hxb   = (unsigned short*)w; w += (size_t)N_NODES * KD * 2;
    unsigned short* mb    = (unsigned short*)w; w += (size_t)N_NODES * KD * 2;  // Hrelu
    unsigned short* aggb  = (unsigned short*)w; w += (size_t)N_NODES * KD * 2;  // gathered h
    unsigned short* WfT   = (unsigned short*)w; w += 2 * 384 * KD * 2;          // fused Wg·Wih^T
    unsigned short* whhb  = (unsigned short*)w; w += 384 * KD * 2;
    unsigned short* lwihb = (unsigned short*)w; w += 512 * KD * 2;
    unsigned short* lwhhb = (unsigned short*)w; w += 512 * KD * 2;
    unsigned short* linwb = (unsigned short*)w; w += 64 * KD * 2;
    int*   rowptr      = (int*)w; w += 50304 * 4;
    int*   bucketTotal = (int*)w; w += 256 * 4;
    int*   bucketBase  = (int*)w; w += 256 * 4;
    int*   bucketCur   = (int*)w; w += 256 * 4;
    int2*  sEdge       = (int2*)w; w += (size_t)E_EDGES * 8;
    int2*  stage_sw    = (int2*)w; w += (size_t)E_EDGES * 8;
    int*   stage_dst   = (int*)w; w += (size_t)E_EDGES * 4;

    dim3 blk(256);

    hipMemsetAsync(bucketTotal, 0, NBUCKETS * sizeof(int), stream);
    prologue<<<PB_TOT, blk, 0, stream>>>(x, H, gru_whh, lstm_wih, lstm_whh, lin_w,
                                         ggc_w, gru_wih, ei,
                                         hb, Hxb, whhb, lwihb, lwhhb, linwb, WfT,
                                         bucketTotal);
    scan_buckets<<<1, blk, 0, stream>>>(bucketTotal, bucketBase, bucketCur);
    fill_bucket<<<256, blk, 0, stream>>>(ei, ew, bucketCur, stage_sw, stage_dst);
    fill_final<<<NBUCKETS, blk, 0, stream>>>(bucketBase, stage_sw, stage_dst,
                                             sEdge, rowptr);

    // layer 0
    gather_agg_bf16<<<(N_NODES * 64 + 255) / 256, blk, 0, stream>>>(
        hb, rowptr, sEdge, aggb);
    gru_fused<<<CELL_BLOCKS, blk, 0, stream>>>(aggb, hb, hb1,
                                               WfT, whhb, gru_bih, gru_bhh);
    // layer 1
    gather_agg_bf16<<<(N_NODES * 64 + 255) / 256, blk, 0, stream>>>(
        hb1, rowptr, sEdge, aggb);
    gru_fused<<<CELL_BLOCKS, blk, 0, stream>>>(aggb, hb1, hb,
                                               WfT + (size_t)384 * KD, whhb, gru_bih, gru_bhh);

    lstm_fused<<<CELL_BLOCKS, blk, 0, stream>>>(hb, Hxb, C, lwihb, lwhhb,
                                                lstm_bih, lstm_bhh, h_out, c_out, mb);
    head_gemm<<<391, blk, 0, stream>>>(mb, linwb, lin_b, out_head);
}